// Round 8
// baseline (748.300 us; speedup 1.0000x reference)
//
#include <hip/hip_runtime.h>
#include <hip/hip_bf16.h>
#include <cstdint>
#include <cstddef>

#define B_TOK 8192
#define DIM   1024
#define HID   4096
#define NEXP  8
#define MAXSLOT 17408  // B_TOK*2 + NEXP*127 padding (128-aligned expert offsets)

typedef __bf16 bf16x8 __attribute__((ext_vector_type(8)));
typedef float  f32x4  __attribute__((ext_vector_type(4)));

__device__ __forceinline__ void load_lds16(const void* g, void* l) {
  __builtin_amdgcn_global_load_lds(
      (const __attribute__((address_space(1))) void*)g,
      (__attribute__((address_space(3))) void*)l, 16, 0, 0);
}

// fp32 -> bf16 RNE
__device__ __forceinline__ uint16_t f2b(float f) {
  uint32_t u = __builtin_bit_cast(uint32_t, f);
  return (uint16_t)((u + 0x7FFFu + ((u >> 16) & 1u)) >> 16);
}
__device__ __forceinline__ float b2f(uint32_t hbits) {
  uint32_t u = hbits << 16;
  return __builtin_bit_cast(float, u);
}

// ---------------- init ----------------
__global__ void init_kernel(int* __restrict__ rows16k, int* __restrict__ counts,
                            int* __restrict__ cursor, float* __restrict__ zeropad) {
  int i = blockIdx.x * 256 + threadIdx.x;
  if (i < MAXSLOT) rows16k[i] = -1;
  if (i < NEXP) { counts[i] = 0; cursor[i] = 0; }
  if (i < 16) zeropad[i] = 0.f;
}

// merged W1+W2 transpose-convert: z = which*8 + e. out[n][m] = bf16(in[m][n]).
// grid(128, 32, 16), block(32,8). which==0: W1 (M=DIM,N=HID); which==1: W2 (M=HID,N=DIM, swap bx/by).
__global__ void transpose_cvt2_kernel(const float* __restrict__ W1, uint16_t* __restrict__ W1b,
                                      const float* __restrict__ W2, uint16_t* __restrict__ W2b) {
  const int which = blockIdx.z >> 3, e = blockIdx.z & 7;
  const float* in = which ? W2 : W1;
  uint16_t* out = which ? W2b : W1b;
  const int M = which ? HID : DIM;
  const int N = which ? DIM : HID;
  const int bx = which ? blockIdx.y : blockIdx.x;
  const int by = which ? blockIdx.x : blockIdx.y;
  __shared__ float tile[32][33];
  const size_t base = (size_t)e * M * N;
  const int x0 = bx * 32, y0 = by * 32;
  const int tx = threadIdx.x, ty = threadIdx.y;
#pragma unroll
  for (int i = 0; i < 4; i++)
    tile[ty + i * 8][tx] = in[base + (size_t)(y0 + ty + i * 8) * N + x0 + tx];
  __syncthreads();
  const int tl = ty * 32 + tx;
  const int r = tl >> 3, c4 = (tl & 7) * 4;
  uint64_t p = (uint64_t)f2b(tile[c4 + 0][r]) | ((uint64_t)f2b(tile[c4 + 1][r]) << 16) |
               ((uint64_t)f2b(tile[c4 + 2][r]) << 32) | ((uint64_t)f2b(tile[c4 + 3][r]) << 48);
  *(uint64_t*)(out + base + (size_t)(x0 + r) * M + y0 + c4) = p;
}

// ---------------- router (+ x -> bf16 conversion fused) ----------------
__global__ void router_kernel(const float* __restrict__ x, const float* __restrict__ Wr,
                              const float* __restrict__ br, int* __restrict__ top_i,
                              float* __restrict__ top_w, int* __restrict__ counts,
                              uint16_t* __restrict__ xb) {
  const int wave = threadIdx.x >> 6, lane = threadIdx.x & 63;
  const int b = blockIdx.x * 4 + wave;
  float acc[NEXP];
#pragma unroll
  for (int e = 0; e < NEXP; e++) acc[e] = 0.f;
  const float* xr = x + (size_t)b * DIM;
  uint16_t* xbr = xb + (size_t)b * DIM;
  for (int d = lane; d < DIM; d += 64) {
    float xv = xr[d];
    xbr[d] = f2b(xv);
    const float4* wr = (const float4*)(Wr + (size_t)d * NEXP);
    float4 w0 = wr[0], w1 = wr[1];
    acc[0] += xv * w0.x; acc[1] += xv * w0.y; acc[2] += xv * w0.z; acc[3] += xv * w0.w;
    acc[4] += xv * w1.x; acc[5] += xv * w1.y; acc[6] += xv * w1.z; acc[7] += xv * w1.w;
  }
#pragma unroll
  for (int e = 0; e < NEXP; e++)
#pragma unroll
    for (int off = 32; off; off >>= 1) acc[e] += __shfl_xor(acc[e], off);
  if (lane == 0) {
    float l[NEXP];
#pragma unroll
    for (int e = 0; e < NEXP; e++) l[e] = acc[e] + br[e];
    int i0 = 0; float v0 = l[0];
#pragma unroll
    for (int e = 1; e < NEXP; e++) if (l[e] > v0) { v0 = l[e]; i0 = e; }
    int i1 = -1; float v1 = -3.4e38f;
#pragma unroll
    for (int e = 0; e < NEXP; e++) if (e != i0 && l[e] > v1) { v1 = l[e]; i1 = e; }
    float w0 = 1.f / (1.f + expf(v1 - v0));
    float w1 = 1.f - w0;
    top_i[b * 2 + 0] = i0; top_i[b * 2 + 1] = i1;
    top_w[b * 2 + 0] = w0; top_w[b * 2 + 1] = w1;
    atomicAdd(&counts[i0], 1);
    atomicAdd(&counts[i1], 1);
  }
}

__global__ void offsets_kernel(const int* __restrict__ counts, int* __restrict__ off_p) {
  int o = 0;
  for (int e = 0; e < NEXP; e++) { off_p[e] = o; o += (counts[e] + 127) & ~127; }
  off_p[NEXP] = o;
}

// wave-aggregated scatter
__global__ void scatter_kernel(const int* __restrict__ top_i, const float* __restrict__ top_w,
                               const int* __restrict__ off_p, int* __restrict__ cursor,
                               int* __restrict__ rows16k, float* __restrict__ wgt,
                               int* __restrict__ slot_of) {
  const int b = blockIdx.x * 256 + threadIdx.x;
  const int lane = threadIdx.x & 63;
#pragma unroll
  for (int k = 0; k < 2; k++) {
    const int e = top_i[b * 2 + k];
    const float w = top_w[b * 2 + k];
    int pos = 0;
#pragma unroll
    for (int ex = 0; ex < NEXP; ex++) {
      unsigned long long m = __ballot(e == ex);
      if (e == ex) {
        int nset = __popcll(m);
        int rank = __popcll(m & ((1ull << lane) - 1ull));
        int leader = __ffsll((long long)m) - 1;
        int base = 0;
        if (lane == leader) base = atomicAdd(&cursor[ex], nset);
        base = __shfl(base, leader);
        pos = off_p[ex] + base + rank;
      }
    }
    rows16k[pos] = b;
    wgt[pos] = w;
    slot_of[b * 2 + k] = pos;
  }
}

// ---------------- 128x128 BK=32 depth-3 counted-vmcnt grouped GEMM ----------------
// 256 threads = 4 waves as 2(M)x2(N); per-wave output 64x64; one MFMA pass per K-step.
// LDS: 4 buffers x (A 8KB + B 8KB) = 64 KiB -> 2 blocks/CU. Prefetch depth 3:
// iter t issues STAGE(t+3) then waits vmcnt(12) (S(t+1..t+3)=12 loads stay in flight).
// Buffer t&3 is only rewritten by S(t+4), issued after the barrier closing COMPUTE(t).
// LDS layout: paired-row [64 rows][128 B]; slot j holds global (row,chunk) with
// j0 = j ^ (lds_row&7), r = lds_row + 64*(j0>>2), chunk = j0&3  -> conflict-free reads.
template<bool GATHER, bool GELU>
__global__ __launch_bounds__(256, 2) void gemm128_kernel(
    const uint16_t* __restrict__ Abase, const uint16_t* __restrict__ Wb,
    const float* __restrict__ bias, const int* __restrict__ rows16k,
    const int* __restrict__ counts, const int* __restrict__ off_p,
    const float* __restrict__ zeropad, uint16_t* __restrict__ outb,
    int Nfull, int Kdim) {
  const int e = blockIdx.z;
  const int ne = counts[e];
  const int rb = blockIdx.y;
  if (rb * 128 >= ne) return;
  const int nbase = blockIdx.x * 128;
  const int sbase = off_p[e] + rb * 128;
  const int nt = Kdim / 32;

  __shared__ __align__(16) uint16_t smem[4 * 8192];  // 64 KiB

  const int tid = threadIdx.x;
  const int lane = tid & 63;
  const int wid = tid >> 6;
  const int wm = wid >> 1, wn = wid & 1;
  const int lr = lane & 15, lh = lane >> 4;

  // staging sources (2 issues per matrix; pre-swizzled chunk per LDS layout)
  const uint16_t* srcA[2]; int stA[2];
  const uint16_t* srcB[2];
#pragma unroll
  for (int is = 0; is < 2; is++) {
    const int ldsrow = (is * 256 + tid) >> 3;        // 0..63
    const int j0 = (tid & 7) ^ (ldsrow & 7);
    const int r = ldsrow + 64 * (j0 >> 2);           // global tile row 0..127
    const int c = (j0 & 3) * 8;                      // chunk offset in elems
    if (GATHER) {
      int tok = rows16k[sbase + r];
      srcA[is] = (tok >= 0) ? (Abase + (size_t)tok * Kdim + c) : (const uint16_t*)zeropad;
      stA[is] = (tok >= 0) ? 32 : 0;
    } else {
      srcA[is] = Abase + (size_t)(sbase + r) * Kdim + c;
      stA[is] = 32;
    }
    srcB[is] = Wb + ((size_t)e * Nfull + nbase + r) * Kdim + c;
  }

  f32x4 acc[4][4];
#pragma unroll
  for (int mi = 0; mi < 4; mi++)
#pragma unroll
    for (int ni = 0; ni < 4; ni++) acc[mi][ni] = (f32x4){0.f, 0.f, 0.f, 0.f};

  auto STAGE = [&](int buf) {
    uint16_t* dA = &smem[buf * 8192];
    uint16_t* dB = dA + 4096;
    load_lds16(srcA[0], dA + tid * 8);
    load_lds16(srcA[1], dA + (256 + tid) * 8);
    load_lds16(srcB[0], dB + tid * 8);
    load_lds16(srcB[1], dB + (256 + tid) * 8);
    srcA[0] += stA[0]; srcA[1] += stA[1]; srcB[0] += 32; srcB[1] += 32;
  };

  const int jA = ((wm << 2) | lh) ^ (lr & 7);   // thread-constant swizzled read slots
  const int jB = ((wn << 2) | lh) ^ (lr & 7);

  auto COMPUTE = [&](int buf) {
    const uint16_t* sA = &smem[buf * 8192];
    const uint16_t* sB = sA + 4096;
    bf16x8 afr[4], bfr[4];
#pragma unroll
    for (int mi = 0; mi < 4; mi++)
      afr[mi] = *(const bf16x8*)&sA[(mi * 16 + lr) * 64 + jA * 8];
#pragma unroll
    for (int ni = 0; ni < 4; ni++)
      bfr[ni] = *(const bf16x8*)&sB[(ni * 16 + lr) * 64 + jB * 8];
#pragma unroll
    for (int mi = 0; mi < 4; mi++)
#pragma unroll
      for (int ni = 0; ni < 4; ni++)
        acc[mi][ni] = __builtin_amdgcn_mfma_f32_16x16x32_bf16(afr[mi], bfr[ni], acc[mi][ni], 0, 0, 0);
  };

  STAGE(0); STAGE(1); STAGE(2);   // depth-3 prologue: 12 loads in flight

  for (int t = 0; t < nt; ++t) {
    if (t + 3 < nt) {
      STAGE((t + 3) & 3);                                  // 16 in flight
      asm volatile("s_waitcnt vmcnt(12)" ::: "memory");    // S(t) landed; 12 stay in flight
    } else if (t + 2 < nt) {
      asm volatile("s_waitcnt vmcnt(8)" ::: "memory");
    } else if (t + 1 < nt) {
      asm volatile("s_waitcnt vmcnt(4)" ::: "memory");
    } else {
      asm volatile("s_waitcnt vmcnt(0)" ::: "memory");
    }
    __builtin_amdgcn_s_barrier();   // all waves: tile t staged (each waited its own loads)
    COMPUTE(t & 3);
    __builtin_amdgcn_s_barrier();   // reads of buf[t&3] done -> S(t+4) may overwrite next iter
  }

  float biasv[4];
#pragma unroll
  for (int ni = 0; ni < 4; ni++)
    biasv[ni] = bias[(size_t)e * Nfull + nbase + wn * 64 + ni * 16 + lr];
#pragma unroll
  for (int mi = 0; mi < 4; mi++)
#pragma unroll
    for (int ni = 0; ni < 4; ni++)
#pragma unroll
      for (int r = 0; r < 4; r++) {
        const int row = wm * 64 + mi * 16 + lh * 4 + r;
        const int col = nbase + wn * 64 + ni * 16 + lr;
        float t = acc[mi][ni][r] + biasv[ni];
        float g;
        if (GELU) {
          float t2 = t * t;
          float v = t * fmaf(0.1029437f, t2, 2.3022085f);
          float ex = exp2f(v);
          float rr = 1.0f / (ex + 1.0f);
          g = t - t * rr;
        } else {
          g = t;
        }
        outb[(size_t)(sbase + row) * Nfull + col] = f2b(g);
      }
}

// ---------------- combine: out[b] = w0*y[slot0] + w1*y[slot1] ----------------
__global__ void combine_kernel(const uint16_t* __restrict__ y, const int* __restrict__ slot_of,
                               const float* __restrict__ top_w, float* __restrict__ out) {
  const int b = blockIdx.x;
  const int t = threadIdx.x;
  const int s0 = slot_of[b * 2], s1 = slot_of[b * 2 + 1];
  const float w0 = top_w[b * 2], w1 = top_w[b * 2 + 1];
  uint64_t p0 = *(const uint64_t*)(y + (size_t)s0 * DIM + t * 4);
  uint64_t p1 = *(const uint64_t*)(y + (size_t)s1 * DIM + t * 4);
  float4 r;
  r.x = w0 * b2f((uint32_t)(p0 >> 0) & 0xFFFFu)  + w1 * b2f((uint32_t)(p1 >> 0) & 0xFFFFu);
  r.y = w0 * b2f((uint32_t)(p0 >> 16) & 0xFFFFu) + w1 * b2f((uint32_t)(p1 >> 16) & 0xFFFFu);
  r.z = w0 * b2f((uint32_t)(p0 >> 32) & 0xFFFFu) + w1 * b2f((uint32_t)(p1 >> 32) & 0xFFFFu);
  r.w = w0 * b2f((uint32_t)(p0 >> 48) & 0xFFFFu) + w1 * b2f((uint32_t)(p1 >> 48) & 0xFFFFu);
  *(float4*)(out + (size_t)b * DIM + t * 4) = r;
}

// ---------------- launch ----------------
extern "C" void kernel_launch(void* const* d_in, const int* in_sizes, int n_in,
                              void* d_out, int out_size, void* d_ws, size_t ws_size,
                              hipStream_t stream) {
  const float* x  = (const float*)d_in[0];
  const float* Wr = (const float*)d_in[1];
  const float* br = (const float*)d_in[2];
  const float* W1 = (const float*)d_in[3];
  const float* b1 = (const float*)d_in[4];
  const float* W2 = (const float*)d_in[5];
  const float* b2 = (const float*)d_in[6];
  float* out = (float*)d_out;

  char* ws = (char*)d_ws;
  uint16_t* W1b = (uint16_t*)ws; ws += (size_t)NEXP * HID * DIM * 2;   // 64 MB
  uint16_t* W2b = (uint16_t*)ws; ws += (size_t)NEXP * DIM * HID * 2;   // 64 MB
  uint16_t* xb  = (uint16_t*)ws; ws += (size_t)B_TOK * DIM * 2;        // 16 MB
  uint16_t* h   = (uint16_t*)ws; ws += (size_t)MAXSLOT * HID * 2;      // 143 MB
  uint16_t* yb  = (uint16_t*)ws; ws += (size_t)MAXSLOT * DIM * 2;      // 36 MB
  int*   top_i  = (int*)ws;   ws += (size_t)B_TOK * 2 * 4;
  float* top_w  = (float*)ws; ws += (size_t)B_TOK * 2 * 4;
  int*   slot_of= (int*)ws;   ws += (size_t)B_TOK * 2 * 4;
  int*   rows16k= (int*)ws;   ws += (size_t)MAXSLOT * 4;
  float* wgt    = (float*)ws; ws += (size_t)MAXSLOT * 4;
  int*   counts = (int*)ws;   ws += 64;
  int*   cursor = (int*)ws;   ws += 64;
  int*   off_p  = (int*)ws;   ws += 64;
  float* zeropad= (float*)ws; ws += 64;

  init_kernel<<<dim3((MAXSLOT + 255) / 256), dim3(256), 0, stream>>>(rows16k, counts, cursor, zeropad);
  transpose_cvt2_kernel<<<dim3(128, 32, 16), dim3(32, 8), 0, stream>>>(W1, W1b, W2, W2b);
  router_kernel<<<dim3(B_TOK / 4), dim3(256), 0, stream>>>(x, Wr, br, top_i, top_w, counts, xb);
  offsets_kernel<<<dim3(1), dim3(1), 0, stream>>>(counts, off_p);
  scatter_kernel<<<dim3(B_TOK / 256), dim3(256), 0, stream>>>(top_i, top_w, off_p, cursor, rows16k, wgt, slot_of);
  // gemm1: h = gelu(gather(x) @ W1^T + b1)   [M=slots, N=HID, K=DIM]
  gemm128_kernel<true, true><<<dim3(HID / 128, MAXSLOT / 128, NEXP), dim3(256), 0, stream>>>(
      xb, W1b, b1, rows16k, counts, off_p, zeropad, h, HID, DIM);
  // gemm2: y = h @ W2^T + b2                  [M=slots, N=DIM, K=HID]
  gemm128_kernel<false, false><<<dim3(DIM / 128, MAXSLOT / 128, NEXP), dim3(256), 0, stream>>>(
      h, W2b, b2, rows16k, counts, off_p, zeropad, yb, DIM, HID);
  combine_kernel<<<dim3(B_TOK), dim3(256), 0, stream>>>(yb, slot_of, top_w, out);
}

// Round 9
// 742.625 us; speedup vs baseline: 1.0076x; 1.0076x over previous
//
#include <hip/hip_runtime.h>
#include <hip/hip_bf16.h>
#include <cstdint>
#include <cstddef>

#define B_TOK 8192
#define DIM   1024
#define HID   4096
#define NEXP  8
#define MAXSLOT 18432  // B_TOK*2 + NEXP*255 padding (256-aligned expert offsets)

typedef __bf16 bf16x8 __attribute__((ext_vector_type(8)));
typedef float  f32x4  __attribute__((ext_vector_type(4)));

__device__ __forceinline__ void load_lds16(const void* g, void* l) {
  __builtin_amdgcn_global_load_lds(
      (const __attribute__((address_space(1))) void*)g,
      (__attribute__((address_space(3))) void*)l, 16, 0, 0);
}

// fp32 -> bf16 RNE
__device__ __forceinline__ uint16_t f2b(float f) {
  uint32_t u = __builtin_bit_cast(uint32_t, f);
  return (uint16_t)((u + 0x7FFFu + ((u >> 16) & 1u)) >> 16);
}
__device__ __forceinline__ float b2f(uint32_t hbits) {
  uint32_t u = hbits << 16;
  return __builtin_bit_cast(float, u);
}

// ---------------- init ----------------
__global__ void init_kernel(int* __restrict__ rows16k, int* __restrict__ counts,
                            int* __restrict__ cursor, float* __restrict__ zeropad) {
  int i = blockIdx.x * 256 + threadIdx.x;
  if (i < MAXSLOT) rows16k[i] = -1;
  if (i < NEXP) { counts[i] = 0; cursor[i] = 0; }
  if (i < 16) zeropad[i] = 0.f;
}

// merged W1+W2 transpose-convert. grid(128, 32, 16), block(32,8).
__global__ void transpose_cvt2_kernel(const float* __restrict__ W1, uint16_t* __restrict__ W1b,
                                      const float* __restrict__ W2, uint16_t* __restrict__ W2b) {
  const int which = blockIdx.z >> 3, e = blockIdx.z & 7;
  const float* in = which ? W2 : W1;
  uint16_t* out = which ? W2b : W1b;
  const int M = which ? HID : DIM;
  const int N = which ? DIM : HID;
  const int bx = which ? blockIdx.y : blockIdx.x;
  const int by = which ? blockIdx.x : blockIdx.y;
  __shared__ float tile[32][33];
  const size_t base = (size_t)e * M * N;
  const int x0 = bx * 32, y0 = by * 32;
  const int tx = threadIdx.x, ty = threadIdx.y;
#pragma unroll
  for (int i = 0; i < 4; i++)
    tile[ty + i * 8][tx] = in[base + (size_t)(y0 + ty + i * 8) * N + x0 + tx];
  __syncthreads();
  const int tl = ty * 32 + tx;
  const int r = tl >> 3, c4 = (tl & 7) * 4;
  uint64_t p = (uint64_t)f2b(tile[c4 + 0][r]) | ((uint64_t)f2b(tile[c4 + 1][r]) << 16) |
               ((uint64_t)f2b(tile[c4 + 2][r]) << 32) | ((uint64_t)f2b(tile[c4 + 3][r]) << 48);
  *(uint64_t*)(out + base + (size_t)(x0 + r) * M + y0 + c4) = p;
}

// ---------------- router (+ x -> bf16 conversion fused) ----------------
__global__ void router_kernel(const float* __restrict__ x, const float* __restrict__ Wr,
                              const float* __restrict__ br, int* __restrict__ top_i,
                              float* __restrict__ top_w, int* __restrict__ counts,
                              uint16_t* __restrict__ xb) {
  const int wave = threadIdx.x >> 6, lane = threadIdx.x & 63;
  const int b = blockIdx.x * 4 + wave;
  float acc[NEXP];
#pragma unroll
  for (int e = 0; e < NEXP; e++) acc[e] = 0.f;
  const float* xr = x + (size_t)b * DIM;
  uint16_t* xbr = xb + (size_t)b * DIM;
  for (int d = lane; d < DIM; d += 64) {
    float xv = xr[d];
    xbr[d] = f2b(xv);
    const float4* wr = (const float4*)(Wr + (size_t)d * NEXP);
    float4 w0 = wr[0], w1 = wr[1];
    acc[0] += xv * w0.x; acc[1] += xv * w0.y; acc[2] += xv * w0.z; acc[3] += xv * w0.w;
    acc[4] += xv * w1.x; acc[5] += xv * w1.y; acc[6] += xv * w1.z; acc[7] += xv * w1.w;
  }
#pragma unroll
  for (int e = 0; e < NEXP; e++)
#pragma unroll
    for (int off = 32; off; off >>= 1) acc[e] += __shfl_xor(acc[e], off);
  if (lane == 0) {
    float l[NEXP];
#pragma unroll
    for (int e = 0; e < NEXP; e++) l[e] = acc[e] + br[e];
    int i0 = 0; float v0 = l[0];
#pragma unroll
    for (int e = 1; e < NEXP; e++) if (l[e] > v0) { v0 = l[e]; i0 = e; }
    int i1 = -1; float v1 = -3.4e38f;
#pragma unroll
    for (int e = 0; e < NEXP; e++) if (e != i0 && l[e] > v1) { v1 = l[e]; i1 = e; }
    float w0 = 1.f / (1.f + expf(v1 - v0));
    float w1 = 1.f - w0;
    top_i[b * 2 + 0] = i0; top_i[b * 2 + 1] = i1;
    top_w[b * 2 + 0] = w0; top_w[b * 2 + 1] = w1;
    atomicAdd(&counts[i0], 1);
    atomicAdd(&counts[i1], 1);
  }
}

__global__ void offsets_kernel(const int* __restrict__ counts, int* __restrict__ off_p) {
  int o = 0;
  for (int e = 0; e < NEXP; e++) { off_p[e] = o; o += (counts[e] + 255) & ~255; }
  off_p[NEXP] = o;
}

// wave-aggregated scatter
__global__ void scatter_kernel(const int* __restrict__ top_i, const float* __restrict__ top_w,
                               const int* __restrict__ off_p, int* __restrict__ cursor,
                               int* __restrict__ rows16k, float* __restrict__ wgt,
                               int* __restrict__ slot_of) {
  const int b = blockIdx.x * 256 + threadIdx.x;
  const int lane = threadIdx.x & 63;
#pragma unroll
  for (int k = 0; k < 2; k++) {
    const int e = top_i[b * 2 + k];
    const float w = top_w[b * 2 + k];
    int pos = 0;
#pragma unroll
    for (int ex = 0; ex < NEXP; ex++) {
      unsigned long long m = __ballot(e == ex);
      if (e == ex) {
        int nset = __popcll(m);
        int rank = __popcll(m & ((1ull << lane) - 1ull));
        int leader = __ffsll((long long)m) - 1;
        int base = 0;
        if (lane == leader) base = atomicAdd(&cursor[ex], nset);
        base = __shfl(base, leader);
        pos = off_p[ex] + base + rank;
      }
    }
    rows16k[pos] = b;
    wgt[pos] = w;
    slot_of[b * 2 + k] = pos;
  }
}

// ---------------- 256x256 BK=64 4-phase/K-tile counted-vmcnt grouped GEMM (m201 port) ----
// 512 threads = 8 waves 2(M)x4(N); per-wave C 128x64 = 8mi x 4ni frags.
// LDS 128 KiB = 2 buf x [A-h0|A-h1|B-h0|B-h1] x 16KB. Half-tile = 2 gloads/thread.
// Stage lead = 6 half-tiles: p0->(t+1,Ah1) p1->(t+1,Bh0) p2->(t+2,Ah0) p3->(t+2,Bh1).
// ONE vmcnt(6) per K-tile at p0 (3 half-tiles stay in flight; never drain in loop).
// Phase p = C-quadrant: p0(mi0-3,ni0-1) p1(mi0-3,ni2-3) p2(mi4-7,ni2-3) p3(mi4-7,ni0-1);
// A-regs persist p0->p1, B-regs p1->p2; 3 barriers/K-tile (p0-mid, p1-end, p3-end).
// Chunk swizzle j_store = j ^ (ldsrow&7) pre-applied on global src; read j = c ^ (lr&7).
template<bool GATHER, bool GELU>
__global__ __launch_bounds__(512, 2) void gemm256_kernel(
    const uint16_t* __restrict__ Abase, const uint16_t* __restrict__ Wb,
    const float* __restrict__ bias, const int* __restrict__ rows16k,
    const int* __restrict__ counts, const int* __restrict__ off_p,
    const float* __restrict__ zeropad, uint16_t* __restrict__ outb,
    int Nfull, int Kdim) {
  const int e = blockIdx.z;
  const int ne = counts[e];
  const int rb = blockIdx.y;
  if (rb * 256 >= ne) return;
  const int nbase = blockIdx.x * 256;
  const int sbase = off_p[e] + rb * 256;
  const int nt = Kdim / 64;

  __shared__ __align__(16) uint16_t smem[2 * 32768];  // 128 KiB

  const int tid = threadIdx.x;
  const int lane = tid & 63;
  const int wid = tid >> 6;
  const int wm = wid >> 2, wn = wid & 3;
  const int lr = lane & 15, lh = lane >> 4;

  // ---- staging sources: [half][iload], pre-swizzled chunk ----
  const uint16_t* srcAh[2][2]; int stA[2][2];
  const uint16_t* srcBh[2][2];
#pragma unroll
  for (int h = 0; h < 2; h++)
#pragma unroll
    for (int il = 0; il < 2; il++) {
      const int idx = il * 512 + tid;
      const int lrow = idx >> 3;                       // 0..127
      const int j0 = (idx & 7) ^ (lrow & 7);           // stored chunk
      const int garow = (lrow >> 6) * 128 + h * 64 + (lrow & 63);   // A tile row
      if (GATHER) {
        int tok = rows16k[sbase + garow];
        srcAh[h][il] = (tok >= 0) ? (Abase + (size_t)tok * Kdim + j0 * 8) : (const uint16_t*)zeropad;
        stA[h][il] = (tok >= 0) ? 64 : 0;
      } else {
        srcAh[h][il] = Abase + (size_t)(sbase + garow) * Kdim + j0 * 8;
        stA[h][il] = 64;
      }
      const int gbrow = (lrow >> 5) * 64 + h * 32 + (lrow & 31);    // B tile row
      srcBh[h][il] = Wb + ((size_t)e * Nfull + nbase + gbrow) * Kdim + j0 * 8;
    }

  auto stageA = [&](int buf, int h) {
    uint16_t* d = &smem[buf * 32768 + h * 8192];
    load_lds16(srcAh[h][0], d + tid * 8);
    load_lds16(srcAh[h][1], d + (512 + tid) * 8);
    srcAh[h][0] += stA[h][0]; srcAh[h][1] += stA[h][1];
  };
  auto stageB = [&](int buf, int h) {
    uint16_t* d = &smem[buf * 32768 + 16384 + h * 8192];
    load_lds16(srcBh[h][0], d + tid * 8);
    load_lds16(srcBh[h][1], d + (512 + tid) * 8);
    srcBh[h][0] += 64; srcBh[h][1] += 64;
  };

  auto ldA = [&](int buf, int mi, int kk) -> bf16x8 {
    const int h = mi >> 2;
    const int row = wm * 64 + (mi & 3) * 16 + lr;      // row within half
    const int j = ((kk << 2) | lh) ^ (lr & 7);
    return *(const bf16x8*)&smem[buf * 32768 + h * 8192 + row * 64 + j * 8];
  };
  auto ldB = [&](int buf, int ni, int kk) -> bf16x8 {
    const int h = ni >> 1;
    const int row = wn * 32 + (ni & 1) * 16 + lr;
    const int j = ((kk << 2) | lh) ^ (lr & 7);
    return *(const bf16x8*)&smem[buf * 32768 + 16384 + h * 8192 + row * 64 + j * 8];
  };

  f32x4 acc[8][4];
#pragma unroll
  for (int mi = 0; mi < 8; mi++)
#pragma unroll
    for (int ni = 0; ni < 4; ni++) acc[mi][ni] = (f32x4){0.f, 0.f, 0.f, 0.f};

  // ---- prologue: tile0 all halves + tile1 {Ah0, Bh1} = 12 loads in flight ----
  stageA(0, 0); stageB(0, 1); stageA(0, 1); stageB(0, 0);
  if (nt > 1) { stageA(1, 0); stageB(1, 1); }

  bf16x8 af[4][2], bf[2][2];

  for (int t = 0; t < nt; ++t) {
    const int cur = t & 1, nxt = cur ^ 1;

    // ================= phase 0: quadrant (mi 0-3, ni 0-1) =================
    if (t + 1 < nt) {
      stageA(nxt, 1);                                  // (t+1, A-h1)
      asm volatile("s_waitcnt vmcnt(6)" ::: "memory"); // tile t fully landed; 3 halves in flight
    } else {
      asm volatile("s_waitcnt vmcnt(0)" ::: "memory");
    }
    __builtin_amdgcn_s_barrier();
#pragma unroll
    for (int m = 0; m < 4; m++) { af[m][0] = ldA(cur, m, 0); af[m][1] = ldA(cur, m, 1); }
#pragma unroll
    for (int n = 0; n < 2; n++) { bf[n][0] = ldB(cur, n, 0); bf[n][1] = ldB(cur, n, 1); }
    __builtin_amdgcn_s_setprio(1);
#pragma unroll
    for (int kk = 0; kk < 2; kk++)
#pragma unroll
      for (int m = 0; m < 4; m++)
#pragma unroll
        for (int n = 0; n < 2; n++)
          acc[m][n] = __builtin_amdgcn_mfma_f32_16x16x32_bf16(af[m][kk], bf[n][kk], acc[m][n], 0, 0, 0);
    __builtin_amdgcn_s_setprio(0);

    // ================= phase 1: quadrant (mi 0-3, ni 2-3); reuse A-regs ======
    if (t + 1 < nt) stageB(nxt, 0);                    // (t+1, B-h0)
#pragma unroll
    for (int n = 0; n < 2; n++) { bf[n][0] = ldB(cur, 2 + n, 0); bf[n][1] = ldB(cur, 2 + n, 1); }
    __builtin_amdgcn_s_setprio(1);
#pragma unroll
    for (int kk = 0; kk < 2; kk++)
#pragma unroll
      for (int m = 0; m < 4; m++)
#pragma unroll
        for (int n = 0; n < 2; n++)
          acc[m][2 + n] = __builtin_amdgcn_mfma_f32_16x16x32_bf16(af[m][kk], bf[n][kk], acc[m][2 + n], 0, 0, 0);
    __builtin_amdgcn_s_setprio(0);
    __builtin_amdgcn_s_barrier();      // A-h0 readers done -> p2 may overwrite it

    // ================= phase 2: quadrant (mi 4-7, ni 2-3); reuse B-regs ======
    if (t + 2 < nt) stageA(cur, 0);                    // (t+2, A-h0) into live buffer
#pragma unroll
    for (int m = 0; m < 4; m++) { af[m][0] = ldA(cur, 4 + m, 0); af[m][1] = ldA(cur, 4 + m, 1); }
    __builtin_amdgcn_s_setprio(1);
#pragma unroll
    for (int kk = 0; kk < 2; kk++)
#pragma unroll
      for (int m = 0; m < 4; m++)
#pragma unroll
        for (int n = 0; n < 2; n++)
          acc[4 + m][2 + n] = __builtin_amdgcn_mfma_f32_16x16x32_bf16(af[m][kk], bf[n][kk], acc[4 + m][2 + n], 0, 0, 0);
    __builtin_amdgcn_s_setprio(0);

    // ================= phase 3: quadrant (mi 4-7, ni 0-1); reload B-h0 =======
    if (t + 2 < nt) stageB(cur, 1);                    // (t+2, B-h1) into live buffer
#pragma unroll
    for (int n = 0; n < 2; n++) { bf[n][0] = ldB(cur, n, 0); bf[n][1] = ldB(cur, n, 1); }
    __builtin_amdgcn_s_setprio(1);
#pragma unroll
    for (int kk = 0; kk < 2; kk++)
#pragma unroll
      for (int m = 0; m < 4; m++)
#pragma unroll
        for (int n = 0; n < 2; n++)
          acc[4 + m][n] = __builtin_amdgcn_mfma_f32_16x16x32_bf16(af[m][kk], bf[n][kk], acc[4 + m][n], 0, 0, 0);
    __builtin_amdgcn_s_setprio(0);
    __builtin_amdgcn_s_barrier();      // tile t reads done -> next p0 stage may proceed
  }

  // ---------------- epilogue ----------------
  float biasv[4];
#pragma unroll
  for (int ni = 0; ni < 4; ni++)
    biasv[ni] = bias[(size_t)e * Nfull + nbase + wn * 64 + ni * 16 + lr];
#pragma unroll
  for (int mi = 0; mi < 8; mi++)
#pragma unroll
    for (int ni = 0; ni < 4; ni++)
#pragma unroll
      for (int r = 0; r < 4; r++) {
        const int row = wm * 128 + mi * 16 + lh * 4 + r;
        const int col = nbase + wn * 64 + ni * 16 + lr;
        float t = acc[mi][ni][r] + biasv[ni];
        float g;
        if (GELU) {
          float t2 = t * t;
          float v = t * fmaf(0.1029437f, t2, 2.3022085f);
          float ex = exp2f(v);
          float rr = 1.0f / (ex + 1.0f);
          g = t - t * rr;
        } else {
          g = t;
        }
        outb[(size_t)(sbase + row) * Nfull + col] = f2b(g);
      }
}

// ---------------- combine: out[b] = w0*y[slot0] + w1*y[slot1] ----------------
__global__ void combine_kernel(const uint16_t* __restrict__ y, const int* __restrict__ slot_of,
                               const float* __restrict__ top_w, float* __restrict__ out) {
  const int b = blockIdx.x;
  const int t = threadIdx.x;
  const int s0 = slot_of[b * 2], s1 = slot_of[b * 2 + 1];
  const float w0 = top_w[b * 2], w1 = top_w[b * 2 + 1];
  uint64_t p0 = *(const uint64_t*)(y + (size_t)s0 * DIM + t * 4);
  uint64_t p1 = *(const uint64_t*)(y + (size_t)s1 * DIM + t * 4);
  float4 r;
  r.x = w0 * b2f((uint32_t)(p0 >> 0) & 0xFFFFu)  + w1 * b2f((uint32_t)(p1 >> 0) & 0xFFFFu);
  r.y = w0 * b2f((uint32_t)(p0 >> 16) & 0xFFFFu) + w1 * b2f((uint32_t)(p1 >> 16) & 0xFFFFu);
  r.z = w0 * b2f((uint32_t)(p0 >> 32) & 0xFFFFu) + w1 * b2f((uint32_t)(p1 >> 32) & 0xFFFFu);
  r.w = w0 * b2f((uint32_t)(p0 >> 48) & 0xFFFFu) + w1 * b2f((uint32_t)(p1 >> 48) & 0xFFFFu);
  *(float4*)(out + (size_t)b * DIM + t * 4) = r;
}

// ---------------- launch ----------------
extern "C" void kernel_launch(void* const* d_in, const int* in_sizes, int n_in,
                              void* d_out, int out_size, void* d_ws, size_t ws_size,
                              hipStream_t stream) {
  const float* x  = (const float*)d_in[0];
  const float* Wr = (const float*)d_in[1];
  const float* br = (const float*)d_in[2];
  const float* W1 = (const float*)d_in[3];
  const float* b1 = (const float*)d_in[4];
  const float* W2 = (const float*)d_in[5];
  const float* b2 = (const float*)d_in[6];
  float* out = (float*)d_out;

  char* ws = (char*)d_ws;
  uint16_t* W1b = (uint16_t*)ws; ws += (size_t)NEXP * HID * DIM * 2;   // 64 MB
  uint16_t* W2b = (uint16_t*)ws; ws += (size_t)NEXP * DIM * HID * 2;   // 64 MB
  uint16_t* xb  = (uint16_t*)ws; ws += (size_t)B_TOK * DIM * 2;        // 16 MB
  uint16_t* h   = (uint16_t*)ws; ws += (size_t)MAXSLOT * HID * 2;      // 151 MB
  uint16_t* yb  = (uint16_t*)ws; ws += (size_t)MAXSLOT * DIM * 2;      // 38 MB
  int*   top_i  = (int*)ws;   ws += (size_t)B_TOK * 2 * 4;
  float* top_w  = (float*)ws; ws += (size_t)B_TOK * 2 * 4;
  int*   slot_of= (int*)ws;   ws += (size_t)B_TOK * 2 * 4;
  int*   rows16k= (int*)ws;   ws += (size_t)MAXSLOT * 4;
  float* wgt    = (float*)ws; ws += (size_t)MAXSLOT * 4;
  int*   counts = (int*)ws;   ws += 64;
  int*   cursor = (int*)ws;   ws += 64;
  int*   off_p  = (int*)ws;   ws += 64;
  float* zeropad= (float*)ws; ws += 64;

  init_kernel<<<dim3((MAXSLOT + 255) / 256), dim3(256), 0, stream>>>(rows16k, counts, cursor, zeropad);
  transpose_cvt2_kernel<<<dim3(128, 32, 16), dim3(32, 8), 0, stream>>>(W1, W1b, W2, W2b);
  router_kernel<<<dim3(B_TOK / 4), dim3(256), 0, stream>>>(x, Wr, br, top_i, top_w, counts, xb);
  offsets_kernel<<<dim3(1), dim3(1), 0, stream>>>(counts, off_p);
  scatter_kernel<<<dim3(B_TOK / 256), dim3(256), 0, stream>>>(top_i, top_w, off_p, cursor, rows16k, wgt, slot_of);
  // gemm1: h = gelu(gather(x) @ W1^T + b1)   [M=slots, N=HID, K=DIM]
  gemm256_kernel<true, true><<<dim3(HID / 256, MAXSLOT / 256, NEXP), dim3(512), 0, stream>>>(
      xb, W1b, b1, rows16k, counts, off_p, zeropad, h, HID, DIM);
  // gemm2: y = h @ W2^T + b2                  [M=slots, N=DIM, K=HID]
  gemm256_kernel<false, false><<<dim3(DIM / 256, MAXSLOT / 256, NEXP), dim3(512), 0, stream>>>(
      h, W2b, b2, rows16k, counts, off_p, zeropad, yb, DIM, HID);
  combine_kernel<<<dim3(B_TOK), dim3(256), 0, stream>>>(yb, slot_of, top_w, out);
}

// Round 12
// 725.702 us; speedup vs baseline: 1.0311x; 1.0233x over previous
//
#include <hip/hip_runtime.h>
#include <hip/hip_bf16.h>
#include <cstdint>
#include <cstddef>

#define B_TOK 8192
#define DIM   1024
#define HID   4096
#define NEXP  8
#define MAXSLOT 17408  // B_TOK*2 + NEXP*127 padding (128-aligned expert offsets)

typedef __bf16 bf16x8 __attribute__((ext_vector_type(8)));
typedef float  f32x4  __attribute__((ext_vector_type(4)));

__device__ __forceinline__ void load_lds16(const void* g, void* l) {
  __builtin_amdgcn_global_load_lds(
      (const __attribute__((address_space(1))) void*)g,
      (__attribute__((address_space(3))) void*)l, 16, 0, 0);
}

// fp32 -> bf16 RNE
__device__ __forceinline__ uint16_t f2b(float f) {
  uint32_t u = __builtin_bit_cast(uint32_t, f);
  return (uint16_t)((u + 0x7FFFu + ((u >> 16) & 1u)) >> 16);
}
__device__ __forceinline__ float b2f(uint32_t hbits) {
  uint32_t u = hbits << 16;
  return __builtin_bit_cast(float, u);
}

// ---------------- init ----------------
__global__ void init_kernel(int* __restrict__ rows16k, int* __restrict__ counts,
                            int* __restrict__ cursor, float* __restrict__ zeropad) {
  int i = blockIdx.x * 256 + threadIdx.x;
  if (i < MAXSLOT) rows16k[i] = -1;
  if (i < NEXP) { counts[i] = 0; cursor[i] = 0; }
  if (i < 16) zeropad[i] = 0.f;
}

// merged W1+W2 transpose-convert. grid(128, 32, 16), block(32,8).
__global__ void transpose_cvt2_kernel(const float* __restrict__ W1, uint16_t* __restrict__ W1b,
                                      const float* __restrict__ W2, uint16_t* __restrict__ W2b) {
  const int which = blockIdx.z >> 3, e = blockIdx.z & 7;
  const float* in = which ? W2 : W1;
  uint16_t* out = which ? W2b : W1b;
  const int M = which ? HID : DIM;
  const int N = which ? DIM : HID;
  const int bx = which ? blockIdx.y : blockIdx.x;
  const int by = which ? blockIdx.x : blockIdx.y;
  __shared__ float tile[32][33];
  const size_t base = (size_t)e * M * N;
  const int x0 = bx * 32, y0 = by * 32;
  const int tx = threadIdx.x, ty = threadIdx.y;
#pragma unroll
  for (int i = 0; i < 4; i++)
    tile[ty + i * 8][tx] = in[base + (size_t)(y0 + ty + i * 8) * N + x0 + tx];
  __syncthreads();
  const int tl = ty * 32 + tx;
  const int r = tl >> 3, c4 = (tl & 7) * 4;
  uint64_t p = (uint64_t)f2b(tile[c4 + 0][r]) | ((uint64_t)f2b(tile[c4 + 1][r]) << 16) |
               ((uint64_t)f2b(tile[c4 + 2][r]) << 32) | ((uint64_t)f2b(tile[c4 + 3][r]) << 48);
  *(uint64_t*)(out + base + (size_t)(x0 + r) * M + y0 + c4) = p;
}

// ---------------- router (+ x -> bf16 conversion fused) ----------------
__global__ void router_kernel(const float* __restrict__ x, const float* __restrict__ Wr,
                              const float* __restrict__ br, int* __restrict__ top_i,
                              float* __restrict__ top_w, int* __restrict__ counts,
                              uint16_t* __restrict__ xb) {
  const int wave = threadIdx.x >> 6, lane = threadIdx.x & 63;
  const int b = blockIdx.x * 4 + wave;
  float acc[NEXP];
#pragma unroll
  for (int e = 0; e < NEXP; e++) acc[e] = 0.f;
  const float* xr = x + (size_t)b * DIM;
  uint16_t* xbr = xb + (size_t)b * DIM;
  for (int d = lane; d < DIM; d += 64) {
    float xv = xr[d];
    xbr[d] = f2b(xv);
    const float4* wr = (const float4*)(Wr + (size_t)d * NEXP);
    float4 w0 = wr[0], w1 = wr[1];
    acc[0] += xv * w0.x; acc[1] += xv * w0.y; acc[2] += xv * w0.z; acc[3] += xv * w0.w;
    acc[4] += xv * w1.x; acc[5] += xv * w1.y; acc[6] += xv * w1.z; acc[7] += xv * w1.w;
  }
#pragma unroll
  for (int e = 0; e < NEXP; e++)
#pragma unroll
    for (int off = 32; off; off >>= 1) acc[e] += __shfl_xor(acc[e], off);
  if (lane == 0) {
    float l[NEXP];
#pragma unroll
    for (int e = 0; e < NEXP; e++) l[e] = acc[e] + br[e];
    int i0 = 0; float v0 = l[0];
#pragma unroll
    for (int e = 1; e < NEXP; e++) if (l[e] > v0) { v0 = l[e]; i0 = e; }
    int i1 = -1; float v1 = -3.4e38f;
#pragma unroll
    for (int e = 0; e < NEXP; e++) if (e != i0 && l[e] > v1) { v1 = l[e]; i1 = e; }
    float w0 = 1.f / (1.f + expf(v1 - v0));
    float w1 = 1.f - w0;
    top_i[b * 2 + 0] = i0; top_i[b * 2 + 1] = i1;
    top_w[b * 2 + 0] = w0; top_w[b * 2 + 1] = w1;
    atomicAdd(&counts[i0], 1);
    atomicAdd(&counts[i1], 1);
  }
}

__global__ void offsets_kernel(const int* __restrict__ counts, int* __restrict__ off_p) {
  int o = 0;
  for (int e = 0; e < NEXP; e++) { off_p[e] = o; o += (counts[e] + 127) & ~127; }
  off_p[NEXP] = o;
}

// wave-aggregated scatter
__global__ void scatter_kernel(const int* __restrict__ top_i, const float* __restrict__ top_w,
                               const int* __restrict__ off_p, int* __restrict__ cursor,
                               int* __restrict__ rows16k, float* __restrict__ wgt,
                               int* __restrict__ slot_of) {
  const int b = blockIdx.x * 256 + threadIdx.x;
  const int lane = threadIdx.x & 63;
#pragma unroll
  for (int k = 0; k < 2; k++) {
    const int e = top_i[b * 2 + k];
    const float w = top_w[b * 2 + k];
    int pos = 0;
#pragma unroll
    for (int ex = 0; ex < NEXP; ex++) {
      unsigned long long m = __ballot(e == ex);
      if (e == ex) {
        int nset = __popcll(m);
        int rank = __popcll(m & ((1ull << lane) - 1ull));
        int leader = __ffsll((long long)m) - 1;
        int base = 0;
        if (lane == leader) base = atomicAdd(&cursor[ex], nset);
        base = __shfl(base, leader);
        pos = off_p[ex] + base + rank;
      }
    }
    rows16k[pos] = b;
    wgt[pos] = w;
    slot_of[b * 2 + k] = pos;
  }
}

// ---------------- 128x128 BK=64 single-buffer grouped GEMM, 4 blocks/CU (m97 clone) ----
// 256 threads = 4 waves as 2(M)x2(N); per-wave output 64x64. LDS 32 KiB single buffer.
// Per K-step: STAGE -> __syncthreads -> COMPUTE -> __syncthreads. No intra-block
// prefetch: cross-BLOCK TLP (4 independent blocks/CU, staggered barriers) hides the
// stage drain (m97/m114 mechanism: 874-912 TF at this exact tile shape on dense GEMM).
// XOR chunk swizzle (chunk ^= row&7) pre-applied on global source, applied on ds_read.
template<bool GATHER, bool GELU>
__global__ __launch_bounds__(256, 4) void gemm128_kernel(
    const uint16_t* __restrict__ Abase, const uint16_t* __restrict__ Wb,
    const float* __restrict__ bias, const int* __restrict__ rows16k,
    const int* __restrict__ counts, const int* __restrict__ off_p,
    const float* __restrict__ zeropad, uint16_t* __restrict__ outb,
    int Nfull, int Kdim) {
  const int e = blockIdx.z;
  const int ne = counts[e];
  const int rb = blockIdx.y;
  if (rb * 128 >= ne) return;
  const int nbase = blockIdx.x * 128;
  const int sbase = off_p[e] + rb * 128;
  const int nt = Kdim / 64;

  __shared__ __align__(16) uint16_t smem[2 * 128 * 64];  // 32 KiB: A 16 KB | B 16 KB

  const int tid = threadIdx.x;
  const int lane = tid & 63;
  const int wid = tid >> 6;
  const int wm = wid >> 1, wn = wid & 1;
  const int lr = lane & 15, lh = lane >> 4;
  const int swz8 = (((tid & 7) ^ ((tid >> 3) & 7)) * 8);

  const uint16_t* srcA[4]; int stA[4];
  const uint16_t* srcB[4];
#pragma unroll
  for (int is = 0; is < 4; is++) {
    const int r = (tid >> 3) + is * 32;
    if (GATHER) {
      int tok = rows16k[sbase + r];
      srcA[is] = (tok >= 0) ? (Abase + (size_t)tok * Kdim + swz8) : (const uint16_t*)zeropad;
      stA[is] = (tok >= 0) ? 64 : 0;
    } else {
      srcA[is] = Abase + (size_t)(sbase + r) * Kdim + swz8;
      stA[is] = 64;
    }
    srcB[is] = Wb + ((size_t)e * Nfull + nbase + r) * Kdim + swz8;
  }

  f32x4 acc[4][4];
#pragma unroll
  for (int mi = 0; mi < 4; mi++)
#pragma unroll
    for (int ni = 0; ni < 4; ni++) acc[mi][ni] = (f32x4){0.f, 0.f, 0.f, 0.f};

  for (int t = 0; t < nt; ++t) {
    // STAGE tile t into the single buffer
    uint16_t* dA = &smem[0];
    uint16_t* dB = dA + 8192;
#pragma unroll
    for (int is = 0; is < 4; is++) {
      load_lds16(srcA[is], dA + (is * 256 + tid) * 8);
      load_lds16(srcB[is], dB + (is * 256 + tid) * 8);
      srcA[is] += stA[is]; srcB[is] += 64;
    }
    __syncthreads();   // drain stage (vmcnt(0)) + barrier

    // COMPUTE tile t
#pragma unroll
    for (int kk = 0; kk < 2; kk++) {
      bf16x8 afr[4], bfr[4];
#pragma unroll
      for (int ni = 0; ni < 4; ni++) {
        const int row = wn * 64 + ni * 16 + lr;
        const int c = (kk * 4 + lh) ^ (lr & 7);
        bfr[ni] = *(const bf16x8*)&dB[row * 64 + c * 8];
      }
#pragma unroll
      for (int mi = 0; mi < 4; mi++) {
        const int row = wm * 64 + mi * 16 + lr;
        const int c = (kk * 4 + lh) ^ (lr & 7);
        afr[mi] = *(const bf16x8*)&dA[row * 64 + c * 8];
      }
#pragma unroll
      for (int mi = 0; mi < 4; mi++)
#pragma unroll
        for (int ni = 0; ni < 4; ni++)
          acc[mi][ni] = __builtin_amdgcn_mfma_f32_16x16x32_bf16(afr[mi], bfr[ni], acc[mi][ni], 0, 0, 0);
    }
    __syncthreads();   // all reads done -> next STAGE may overwrite
  }

  float biasv[4];
#pragma unroll
  for (int ni = 0; ni < 4; ni++)
    biasv[ni] = bias[(size_t)e * Nfull + nbase + wn * 64 + ni * 16 + lr];
#pragma unroll
  for (int mi = 0; mi < 4; mi++)
#pragma unroll
    for (int ni = 0; ni < 4; ni++)
#pragma unroll
      for (int r = 0; r < 4; r++) {
        const int row = wm * 64 + mi * 16 + lh * 4 + r;
        const int col = nbase + wn * 64 + ni * 16 + lr;
        float t = acc[mi][ni][r] + biasv[ni];
        float g;
        if (GELU) {
          // tanh-form GELU via exp2: g = t - t/(2^(t*(c1 + c2*t^2)) + 1)
          float t2 = t * t;
          float v = t * fmaf(0.1029437f, t2, 2.3022085f);
          float ex = exp2f(v);
          float rr = 1.0f / (ex + 1.0f);
          g = t - t * rr;
        } else {
          g = t;
        }
        outb[(size_t)(sbase + row) * Nfull + col] = f2b(g);
      }
}

// ---------------- combine: out[b] = w0*y[slot0] + w1*y[slot1] ----------------
__global__ void combine_kernel(const uint16_t* __restrict__ y, const int* __restrict__ slot_of,
                               const float* __restrict__ top_w, float* __restrict__ out) {
  const int b = blockIdx.x;
  const int t = threadIdx.x;
  const int s0 = slot_of[b * 2], s1 = slot_of[b * 2 + 1];
  const float w0 = top_w[b * 2], w1 = top_w[b * 2 + 1];
  uint64_t p0 = *(const uint64_t*)(y + (size_t)s0 * DIM + t * 4);
  uint64_t p1 = *(const uint64_t*)(y + (size_t)s1 * DIM + t * 4);
  float4 r;
  r.x = w0 * b2f((uint32_t)(p0 >> 0) & 0xFFFFu)  + w1 * b2f((uint32_t)(p1 >> 0) & 0xFFFFu);
  r.y = w0 * b2f((uint32_t)(p0 >> 16) & 0xFFFFu) + w1 * b2f((uint32_t)(p1 >> 16) & 0xFFFFu);
  r.z = w0 * b2f((uint32_t)(p0 >> 32) & 0xFFFFu) + w1 * b2f((uint32_t)(p1 >> 32) & 0xFFFFu);
  r.w = w0 * b2f((uint32_t)(p0 >> 48) & 0xFFFFu) + w1 * b2f((uint32_t)(p1 >> 48) & 0xFFFFu);
  *(float4*)(out + (size_t)b * DIM + t * 4) = r;
}

// ---------------- launch ----------------
extern "C" void kernel_launch(void* const* d_in, const int* in_sizes, int n_in,
                              void* d_out, int out_size, void* d_ws, size_t ws_size,
                              hipStream_t stream) {
  const float* x  = (const float*)d_in[0];
  const float* Wr = (const float*)d_in[1];
  const float* br = (const float*)d_in[2];
  const float* W1 = (const float*)d_in[3];
  const float* b1 = (const float*)d_in[4];
  const float* W2 = (const float*)d_in[5];
  const float* b2 = (const float*)d_in[6];
  float* out = (float*)d_out;

  char* ws = (char*)d_ws;
  uint16_t* W1b = (uint16_t*)ws; ws += (size_t)NEXP * HID * DIM * 2;   // 64 MB
  uint16_t* W2b = (uint16_t*)ws; ws += (size_t)NEXP * DIM * HID * 2;   // 64 MB
  uint16_t* xb  = (uint16_t*)ws; ws += (size_t)B_TOK * DIM * 2;        // 16 MB
  uint16_t* h   = (uint16_t*)ws; ws += (size_t)MAXSLOT * HID * 2;      // 143 MB
  uint16_t* yb  = (uint16_t*)ws; ws += (size_t)MAXSLOT * DIM * 2;      // 36 MB
  int*   top_i  = (int*)ws;   ws += (size_t)B_TOK * 2 * 4;
  float* top_w  = (float*)ws; ws += (size_t)B_TOK * 2 * 4;
  int*   slot_of= (int*)ws;   ws += (size_t)B_TOK * 2 * 4;
  int*   rows16k= (int*)ws;   ws += (size_t)MAXSLOT * 4;
  float* wgt    = (float*)ws; ws += (size_t)MAXSLOT * 4;
  int*   counts = (int*)ws;   ws += 64;
  int*   cursor = (int*)ws;   ws += 64;
  int*   off_p  = (int*)ws;   ws += 64;
  float* zeropad= (float*)ws; ws += 64;

  init_kernel<<<dim3((MAXSLOT + 255) / 256), dim3(256), 0, stream>>>(rows16k, counts, cursor, zeropad);
  transpose_cvt2_kernel<<<dim3(128, 32, 16), dim3(32, 8), 0, stream>>>(W1, W1b, W2, W2b);
  router_kernel<<<dim3(B_TOK / 4), dim3(256), 0, stream>>>(x, Wr, br, top_i, top_w, counts, xb);
  offsets_kernel<<<dim3(1), dim3(1), 0, stream>>>(counts, off_p);
  scatter_kernel<<<dim3(B_TOK / 256), dim3(256), 0, stream>>>(top_i, top_w, off_p, cursor, rows16k, wgt, slot_of);
  // gemm1: h = gelu(gather(x) @ W1^T + b1)   [M=slots, N=HID, K=DIM]
  gemm128_kernel<true, true><<<dim3(HID / 128, MAXSLOT / 128, NEXP), dim3(256), 0, stream>>>(
      xb, W1b, b1, rows16k, counts, off_p, zeropad, h, HID, DIM);
  // gemm2: y = h @ W2^T + b2                  [M=slots, N=DIM, K=HID]
  gemm128_kernel<false, false><<<dim3(DIM / 128, MAXSLOT / 128, NEXP), dim3(256), 0, stream>>>(
      h, W2b, b2, rows16k, counts, off_p, zeropad, yb, DIM, HID);
  combine_kernel<<<dim3(B_TOK), dim3(256), 0, stream>>>(yb, slot_of, top_w, out);
}

// Round 13
// 692.825 us; speedup vs baseline: 1.0801x; 1.0475x over previous
//
#include <hip/hip_runtime.h>
#include <hip/hip_bf16.h>
#include <cstdint>
#include <cstddef>

#define B_TOK 8192
#define DIM   1024
#define HID   4096
#define NEXP  8
#define MAXSLOT 17408  // B_TOK*2 + NEXP*127 padding (128-aligned expert offsets)

typedef __bf16 bf16x8 __attribute__((ext_vector_type(8)));
typedef float  f32x4  __attribute__((ext_vector_type(4)));

__device__ __forceinline__ void load_lds16(const void* g, void* l) {
  __builtin_amdgcn_global_load_lds(
      (const __attribute__((address_space(1))) void*)g,
      (__attribute__((address_space(3))) void*)l, 16, 0, 0);
}

// fp32 -> bf16 RNE
__device__ __forceinline__ uint16_t f2b(float f) {
  uint32_t u = __builtin_bit_cast(uint32_t, f);
  return (uint16_t)((u + 0x7FFFu + ((u >> 16) & 1u)) >> 16);
}
__device__ __forceinline__ float b2f(uint32_t hbits) {
  uint32_t u = hbits << 16;
  return __builtin_bit_cast(float, u);
}

// ---------------- init ----------------
__global__ void init_kernel(int* __restrict__ rows16k, int* __restrict__ counts,
                            int* __restrict__ cursor, float* __restrict__ zeropad) {
  int i = blockIdx.x * 256 + threadIdx.x;
  if (i < MAXSLOT) rows16k[i] = -1;
  if (i < NEXP) { counts[i] = 0; cursor[i] = 0; }
  if (i < 16) zeropad[i] = 0.f;
}

// merged W1+W2 transpose-convert. grid(128, 32, 16), block(32,8).
__global__ void transpose_cvt2_kernel(const float* __restrict__ W1, uint16_t* __restrict__ W1b,
                                      const float* __restrict__ W2, uint16_t* __restrict__ W2b) {
  const int which = blockIdx.z >> 3, e = blockIdx.z & 7;
  const float* in = which ? W2 : W1;
  uint16_t* out = which ? W2b : W1b;
  const int M = which ? HID : DIM;
  const int N = which ? DIM : HID;
  const int bx = which ? blockIdx.y : blockIdx.x;
  const int by = which ? blockIdx.x : blockIdx.y;
  __shared__ float tile[32][33];
  const size_t base = (size_t)e * M * N;
  const int x0 = bx * 32, y0 = by * 32;
  const int tx = threadIdx.x, ty = threadIdx.y;
#pragma unroll
  for (int i = 0; i < 4; i++)
    tile[ty + i * 8][tx] = in[base + (size_t)(y0 + ty + i * 8) * N + x0 + tx];
  __syncthreads();
  const int tl = ty * 32 + tx;
  const int r = tl >> 3, c4 = (tl & 7) * 4;
  uint64_t p = (uint64_t)f2b(tile[c4 + 0][r]) | ((uint64_t)f2b(tile[c4 + 1][r]) << 16) |
               ((uint64_t)f2b(tile[c4 + 2][r]) << 32) | ((uint64_t)f2b(tile[c4 + 3][r]) << 48);
  *(uint64_t*)(out + base + (size_t)(x0 + r) * M + y0 + c4) = p;
}

// ---------------- router (+ x -> bf16 conversion fused) ----------------
__global__ void router_kernel(const float* __restrict__ x, const float* __restrict__ Wr,
                              const float* __restrict__ br, int* __restrict__ top_i,
                              float* __restrict__ top_w, int* __restrict__ counts,
                              uint16_t* __restrict__ xb) {
  const int wave = threadIdx.x >> 6, lane = threadIdx.x & 63;
  const int b = blockIdx.x * 4 + wave;
  float acc[NEXP];
#pragma unroll
  for (int e = 0; e < NEXP; e++) acc[e] = 0.f;
  const float* xr = x + (size_t)b * DIM;
  uint16_t* xbr = xb + (size_t)b * DIM;
  for (int d = lane; d < DIM; d += 64) {
    float xv = xr[d];
    xbr[d] = f2b(xv);
    const float4* wr = (const float4*)(Wr + (size_t)d * NEXP);
    float4 w0 = wr[0], w1 = wr[1];
    acc[0] += xv * w0.x; acc[1] += xv * w0.y; acc[2] += xv * w0.z; acc[3] += xv * w0.w;
    acc[4] += xv * w1.x; acc[5] += xv * w1.y; acc[6] += xv * w1.z; acc[7] += xv * w1.w;
  }
#pragma unroll
  for (int e = 0; e < NEXP; e++)
#pragma unroll
    for (int off = 32; off; off >>= 1) acc[e] += __shfl_xor(acc[e], off);
  if (lane == 0) {
    float l[NEXP];
#pragma unroll
    for (int e = 0; e < NEXP; e++) l[e] = acc[e] + br[e];
    int i0 = 0; float v0 = l[0];
#pragma unroll
    for (int e = 1; e < NEXP; e++) if (l[e] > v0) { v0 = l[e]; i0 = e; }
    int i1 = -1; float v1 = -3.4e38f;
#pragma unroll
    for (int e = 0; e < NEXP; e++) if (e != i0 && l[e] > v1) { v1 = l[e]; i1 = e; }
    float w0 = 1.f / (1.f + expf(v1 - v0));
    float w1 = 1.f - w0;
    top_i[b * 2 + 0] = i0; top_i[b * 2 + 1] = i1;
    top_w[b * 2 + 0] = w0; top_w[b * 2 + 1] = w1;
    atomicAdd(&counts[i0], 1);
    atomicAdd(&counts[i1], 1);
  }
}

__global__ void offsets_kernel(const int* __restrict__ counts, int* __restrict__ off_p) {
  int o = 0;
  for (int e = 0; e < NEXP; e++) { off_p[e] = o; o += (counts[e] + 127) & ~127; }
  off_p[NEXP] = o;
}

// wave-aggregated scatter
__global__ void scatter_kernel(const int* __restrict__ top_i, const float* __restrict__ top_w,
                               const int* __restrict__ off_p, int* __restrict__ cursor,
                               int* __restrict__ rows16k, float* __restrict__ wgt,
                               int* __restrict__ slot_of) {
  const int b = blockIdx.x * 256 + threadIdx.x;
  const int lane = threadIdx.x & 63;
#pragma unroll
  for (int k = 0; k < 2; k++) {
    const int e = top_i[b * 2 + k];
    const float w = top_w[b * 2 + k];
    int pos = 0;
#pragma unroll
    for (int ex = 0; ex < NEXP; ex++) {
      unsigned long long m = __ballot(e == ex);
      if (e == ex) {
        int nset = __popcll(m);
        int rank = __popcll(m & ((1ull << lane) - 1ull));
        int leader = __ffsll((long long)m) - 1;
        int base = 0;
        if (lane == leader) base = atomicAdd(&cursor[ex], nset);
        base = __shfl(base, leader);
        pos = off_p[ex] + base + rank;
      }
    }
    rows16k[pos] = b;
    wgt[pos] = w;
    slot_of[b * 2 + k] = pos;
  }
}

// ---------------- 128x128 BK=64 single-buffer grouped GEMM, 4 blocks/CU ----------------
// Same body as round 12 (m97 shape: 4 waves 2Mx2N, 32 KiB single-buffer LDS,
// STAGE -> syncthreads -> COMPUTE -> syncthreads, XOR chunk swizzle).
// NEW: expert->XCD chunking. blockIdx.x = expert is the FASTEST grid dim, so
// linear block id ≡ expert (mod 8) -> XCD round-robin pins each expert's blocks
// to one XCD (m09/m157). Kills the 8x cross-XCD L2 panel duplication seen in R12
// (FETCH_SIZE 666 MB: every panel fetched into all 8 incoherent L2s).
// blockIdx.y = N-tile, blockIdx.z = M-tile (within-XCD order unchanged vs R12).
template<bool GATHER, bool GELU>
__global__ __launch_bounds__(256, 4) void gemm128_kernel(
    const uint16_t* __restrict__ Abase, const uint16_t* __restrict__ Wb,
    const float* __restrict__ bias, const int* __restrict__ rows16k,
    const int* __restrict__ counts, const int* __restrict__ off_p,
    const float* __restrict__ zeropad, uint16_t* __restrict__ outb,
    int Nfull, int Kdim) {
  const int e = blockIdx.x;            // fastest dim -> XCD pinning
  const int ne = counts[e];
  const int rb = blockIdx.z;
  if (rb * 128 >= ne) return;
  const int nbase = blockIdx.y * 128;
  const int sbase = off_p[e] + rb * 128;
  const int nt = Kdim / 64;

  __shared__ __align__(16) uint16_t smem[2 * 128 * 64];  // 32 KiB: A 16 KB | B 16 KB

  const int tid = threadIdx.x;
  const int lane = tid & 63;
  const int wid = tid >> 6;
  const int wm = wid >> 1, wn = wid & 1;
  const int lr = lane & 15, lh = lane >> 4;
  const int swz8 = (((tid & 7) ^ ((tid >> 3) & 7)) * 8);

  const uint16_t* srcA[4]; int stA[4];
  const uint16_t* srcB[4];
#pragma unroll
  for (int is = 0; is < 4; is++) {
    const int r = (tid >> 3) + is * 32;
    if (GATHER) {
      int tok = rows16k[sbase + r];
      srcA[is] = (tok >= 0) ? (Abase + (size_t)tok * Kdim + swz8) : (const uint16_t*)zeropad;
      stA[is] = (tok >= 0) ? 64 : 0;
    } else {
      srcA[is] = Abase + (size_t)(sbase + r) * Kdim + swz8;
      stA[is] = 64;
    }
    srcB[is] = Wb + ((size_t)e * Nfull + nbase + r) * Kdim + swz8;
  }

  f32x4 acc[4][4];
#pragma unroll
  for (int mi = 0; mi < 4; mi++)
#pragma unroll
    for (int ni = 0; ni < 4; ni++) acc[mi][ni] = (f32x4){0.f, 0.f, 0.f, 0.f};

  for (int t = 0; t < nt; ++t) {
    // STAGE tile t into the single buffer
    uint16_t* dA = &smem[0];
    uint16_t* dB = dA + 8192;
#pragma unroll
    for (int is = 0; is < 4; is++) {
      load_lds16(srcA[is], dA + (is * 256 + tid) * 8);
      load_lds16(srcB[is], dB + (is * 256 + tid) * 8);
      srcA[is] += stA[is]; srcB[is] += 64;
    }
    __syncthreads();   // drain stage (vmcnt(0)) + barrier

    // COMPUTE tile t
#pragma unroll
    for (int kk = 0; kk < 2; kk++) {
      bf16x8 afr[4], bfr[4];
#pragma unroll
      for (int ni = 0; ni < 4; ni++) {
        const int row = wn * 64 + ni * 16 + lr;
        const int c = (kk * 4 + lh) ^ (lr & 7);
        bfr[ni] = *(const bf16x8*)&dB[row * 64 + c * 8];
      }
#pragma unroll
      for (int mi = 0; mi < 4; mi++) {
        const int row = wm * 64 + mi * 16 + lr;
        const int c = (kk * 4 + lh) ^ (lr & 7);
        afr[mi] = *(const bf16x8*)&dA[row * 64 + c * 8];
      }
#pragma unroll
      for (int mi = 0; mi < 4; mi++)
#pragma unroll
        for (int ni = 0; ni < 4; ni++)
          acc[mi][ni] = __builtin_amdgcn_mfma_f32_16x16x32_bf16(afr[mi], bfr[ni], acc[mi][ni], 0, 0, 0);
    }
    __syncthreads();   // all reads done -> next STAGE may overwrite
  }

  float biasv[4];
#pragma unroll
  for (int ni = 0; ni < 4; ni++)
    biasv[ni] = bias[(size_t)e * Nfull + nbase + wn * 64 + ni * 16 + lr];
#pragma unroll
  for (int mi = 0; mi < 4; mi++)
#pragma unroll
    for (int ni = 0; ni < 4; ni++)
#pragma unroll
      for (int r = 0; r < 4; r++) {
        const int row = wm * 64 + mi * 16 + lh * 4 + r;
        const int col = nbase + wn * 64 + ni * 16 + lr;
        float t = acc[mi][ni][r] + biasv[ni];
        float g;
        if (GELU) {
          // tanh-form GELU via exp2: g = t - t/(2^(t*(c1 + c2*t^2)) + 1)
          float t2 = t * t;
          float v = t * fmaf(0.1029437f, t2, 2.3022085f);
          float ex = exp2f(v);
          float rr = 1.0f / (ex + 1.0f);
          g = t - t * rr;
        } else {
          g = t;
        }
        outb[(size_t)(sbase + row) * Nfull + col] = f2b(g);
      }
}

// ---------------- combine: out[b] = w0*y[slot0] + w1*y[slot1] ----------------
__global__ void combine_kernel(const uint16_t* __restrict__ y, const int* __restrict__ slot_of,
                               const float* __restrict__ top_w, float* __restrict__ out) {
  const int b = blockIdx.x;
  const int t = threadIdx.x;
  const int s0 = slot_of[b * 2], s1 = slot_of[b * 2 + 1];
  const float w0 = top_w[b * 2], w1 = top_w[b * 2 + 1];
  uint64_t p0 = *(const uint64_t*)(y + (size_t)s0 * DIM + t * 4);
  uint64_t p1 = *(const uint64_t*)(y + (size_t)s1 * DIM + t * 4);
  float4 r;
  r.x = w0 * b2f((uint32_t)(p0 >> 0) & 0xFFFFu)  + w1 * b2f((uint32_t)(p1 >> 0) & 0xFFFFu);
  r.y = w0 * b2f((uint32_t)(p0 >> 16) & 0xFFFFu) + w1 * b2f((uint32_t)(p1 >> 16) & 0xFFFFu);
  r.z = w0 * b2f((uint32_t)(p0 >> 32) & 0xFFFFu) + w1 * b2f((uint32_t)(p1 >> 32) & 0xFFFFu);
  r.w = w0 * b2f((uint32_t)(p0 >> 48) & 0xFFFFu) + w1 * b2f((uint32_t)(p1 >> 48) & 0xFFFFu);
  *(float4*)(out + (size_t)b * DIM + t * 4) = r;
}

// ---------------- launch ----------------
extern "C" void kernel_launch(void* const* d_in, const int* in_sizes, int n_in,
                              void* d_out, int out_size, void* d_ws, size_t ws_size,
                              hipStream_t stream) {
  const float* x  = (const float*)d_in[0];
  const float* Wr = (const float*)d_in[1];
  const float* br = (const float*)d_in[2];
  const float* W1 = (const float*)d_in[3];
  const float* b1 = (const float*)d_in[4];
  const float* W2 = (const float*)d_in[5];
  const float* b2 = (const float*)d_in[6];
  float* out = (float*)d_out;

  char* ws = (char*)d_ws;
  uint16_t* W1b = (uint16_t*)ws; ws += (size_t)NEXP * HID * DIM * 2;   // 64 MB
  uint16_t* W2b = (uint16_t*)ws; ws += (size_t)NEXP * DIM * HID * 2;   // 64 MB
  uint16_t* xb  = (uint16_t*)ws; ws += (size_t)B_TOK * DIM * 2;        // 16 MB
  uint16_t* h   = (uint16_t*)ws; ws += (size_t)MAXSLOT * HID * 2;      // 143 MB
  uint16_t* yb  = (uint16_t*)ws; ws += (size_t)MAXSLOT * DIM * 2;      // 36 MB
  int*   top_i  = (int*)ws;   ws += (size_t)B_TOK * 2 * 4;
  float* top_w  = (float*)ws; ws += (size_t)B_TOK * 2 * 4;
  int*   slot_of= (int*)ws;   ws += (size_t)B_TOK * 2 * 4;
  int*   rows16k= (int*)ws;   ws += (size_t)MAXSLOT * 4;
  float* wgt    = (float*)ws; ws += (size_t)MAXSLOT * 4;
  int*   counts = (int*)ws;   ws += 64;
  int*   cursor = (int*)ws;   ws += 64;
  int*   off_p  = (int*)ws;   ws += 64;
  float* zeropad= (float*)ws; ws += 64;

  init_kernel<<<dim3((MAXSLOT + 255) / 256), dim3(256), 0, stream>>>(rows16k, counts, cursor, zeropad);
  transpose_cvt2_kernel<<<dim3(128, 32, 16), dim3(32, 8), 0, stream>>>(W1, W1b, W2, W2b);
  router_kernel<<<dim3(B_TOK / 4), dim3(256), 0, stream>>>(x, Wr, br, top_i, top_w, counts, xb);
  offsets_kernel<<<dim3(1), dim3(1), 0, stream>>>(counts, off_p);
  scatter_kernel<<<dim3(B_TOK / 256), dim3(256), 0, stream>>>(top_i, top_w, off_p, cursor, rows16k, wgt, slot_of);
  // gemm1: h = gelu(gather(x) @ W1^T + b1)   [M=slots, N=HID, K=DIM]
  // grid(x=expert -> XCD pin, y=N-tiles, z=M-tiles)
  gemm128_kernel<true, true><<<dim3(NEXP, HID / 128, MAXSLOT / 128), dim3(256), 0, stream>>>(
      xb, W1b, b1, rows16k, counts, off_p, zeropad, h, HID, DIM);
  // gemm2: y = h @ W2^T + b2                  [M=slots, N=DIM, K=HID]
  gemm128_kernel<false, false><<<dim3(NEXP, DIM / 128, MAXSLOT / 128), dim3(256), 0, stream>>>(
      h, W2b, b2, rows16k, counts, off_p, zeropad, yb, DIM, HID);
  combine_kernel<<<dim3(B_TOK), dim3(256), 0, stream>>>(yb, slot_of, top_w, out);
}